// Round 1
// baseline (163.831 us; speedup 1.0000x reference)
//
#include <hip/hip_runtime.h>

// AE (associative-embedding) loss.
// B=64 batches, N=65536 locations, T=8 tag dim, M=30 people, K=17 joints.
// Inputs: d_in[0] = tags [B,N,T] float32, d_in[1] = keypoints [B,M,K,2] int32.
// Output: d_out = [B,2] float32, per batch [push, pull].

#define Bc 64
#define Nc 65536
#define Tc 8
#define Mc 30
#define Kc 17

__global__ __launch_bounds__(256) void ae_loss_kernel(
    const float* __restrict__ tags,
    const int*   __restrict__ kp,
    float*       __restrict__ out)
{
    const int b   = blockIdx.x;
    const int tid = threadIdx.x;

    // LDS: gathered tag vectors + per-person stats (~19 KB total)
    __shared__ float g[Mc * Kc * Tc];    // [M][K][T] gathered tags
    __shared__ float vf[Mc * Kc];        // validity flags
    __shared__ float mean_s[Mc * Tc];    // per-person mean tag
    __shared__ float pull_p[Mc];         // per-person pull
    __shared__ float cnt_s[Mc];          // valid-joint count
    __shared__ float wsum[4];            // per-wave push partials

    const float* tb = tags + (size_t)b * Nc * Tc;
    const int*   kb = kp   + (size_t)b * Mc * Kc * 2;

    // ---- Phase 1: gather tag vectors at keypoint locations ----
    for (int p = tid; p < Mc * Kc; p += 256) {
        int idx = kb[2 * p];
        int v   = kb[2 * p + 1];
        vf[p] = (v > 0) ? 1.0f : 0.0f;
        // 32-byte aligned: idx*T floats = idx*32 bytes
        const float4* src = (const float4*)(tb + (size_t)idx * Tc);
        float4 a = src[0];
        float4 c = src[1];
        float* gd = g + p * Tc;
        *(float4*)(gd)     = a;
        *(float4*)(gd + 4) = c;
    }
    __syncthreads();

    // ---- Phase 2: per-person mean + pull (one thread per person) ----
    if (tid < Mc) {
        const int m = tid;
        float c = 0.0f;
        float s[Tc];
        #pragma unroll
        for (int t = 0; t < Tc; ++t) s[t] = 0.0f;

        for (int k = 0; k < Kc; ++k) {
            float v = vf[m * Kc + k];
            c += v;
            #pragma unroll
            for (int t = 0; t < Tc; ++t)
                s[t] += g[(m * Kc + k) * Tc + t] * v;
        }
        float sc  = fmaxf(c, 1.0f);
        float inv = 1.0f / sc;
        #pragma unroll
        for (int t = 0; t < Tc; ++t) {
            s[t] *= inv;                 // mean
            mean_s[m * Tc + t] = s[t];
        }
        float pp = 0.0f;
        for (int k = 0; k < Kc; ++k) {
            float sq = 0.0f;
            #pragma unroll
            for (int t = 0; t < Tc; ++t) {
                float d = g[(m * Kc + k) * Tc + t] - s[t];
                sq += d * d;
            }
            pp += (sq * 0.125f) * vf[m * Kc + k];   // mean over T=8
        }
        pull_p[m] = pp * inv;
        cnt_s[m]  = c;
    }
    __syncthreads();

    // ---- Phase 3: push over distinct valid person pairs ----
    float local = 0.0f;
    for (int p = tid; p < Mc * Mc; p += 256) {
        int i = p / Mc;
        int j = p - i * Mc;
        if (i != j && cnt_s[i] > 0.0f && cnt_s[j] > 0.0f) {
            float d2 = 0.0f;
            #pragma unroll
            for (int t = 0; t < Tc; ++t) {
                float d = mean_s[i * Tc + t] - mean_s[j * Tc + t];
                d2 += d * d;
            }
            local += expf(-d2);
        }
    }
    // wave64 shuffle reduce, then LDS across the 4 waves
    #pragma unroll
    for (int off = 32; off > 0; off >>= 1)
        local += __shfl_down(local, off, 64);
    if ((tid & 63) == 0) wsum[tid >> 6] = local;
    __syncthreads();

    if (tid == 0) {
        float push_tot = wsum[0] + wsum[1] + wsum[2] + wsum[3];
        float n = 0.0f, pull = 0.0f;
        for (int m = 0; m < Mc; ++m) {
            n    += (cnt_s[m] > 0.0f) ? 1.0f : 0.0f;
            pull += pull_p[m];
        }
        pull /= fmaxf(n, 1.0f);
        float push = 0.0f;
        if (n > 1.0f)
            push = push_tot / fmaxf(n * (n - 1.0f), 1.0f) * 0.5f;
        out[2 * b + 0] = push;
        out[2 * b + 1] = pull;
    }
}

extern "C" void kernel_launch(void* const* d_in, const int* in_sizes, int n_in,
                              void* d_out, int out_size, void* d_ws, size_t ws_size,
                              hipStream_t stream) {
    const float* tags = (const float*)d_in[0];
    const int*   kp   = (const int*)d_in[1];
    float*       out  = (float*)d_out;
    ae_loss_kernel<<<Bc, 256, 0, stream>>>(tags, kp, out);
}

// Round 2
// 161.979 us; speedup vs baseline: 1.0114x; 1.0114x over previous
//
#include <hip/hip_runtime.h>

// AE (associative-embedding) loss.
// B=64 batches, N=65536 locations, T=8 tag dim, M=30 people, K=17 joints.
// Inputs: d_in[0] = tags [B,N,T] float32, d_in[1] = keypoints [B,M,K,2] int32.
// Output: d_out = [B,2] float32, per batch [push, pull].
//
// R2: 512-thread block — all 510 gathers issue in one pass (max latency
// overlap); phase 2 parallelized over M*T (mean) and M*K (per-joint sq)
// instead of one thread per person. Kernel itself is latency-bound and
// ~5-10 us; measured dur_us is dominated by harness re-poison fills
// (512 MB @ 79 us each per rocprof R1).

#define Bc 64
#define Nc 65536
#define Tc 8
#define Mc 30
#define Kc 17
#define THREADS 512

__global__ __launch_bounds__(THREADS) void ae_loss_kernel(
    const float* __restrict__ tags,
    const int*   __restrict__ kp,
    float*       __restrict__ out)
{
    const int b   = blockIdx.x;
    const int tid = threadIdx.x;

    __shared__ float g[Mc * Kc * Tc];    // gathered tag vectors [M*K][T]
    __shared__ float vf[Mc * Kc];        // validity flags
    __shared__ float mean_s[Mc * Tc];    // per-person mean tag
    __shared__ float sq_s[Mc * Kc];      // per-joint masked squared diff
    __shared__ float cnt_s[Mc];          // valid-joint count
    __shared__ float pull_p[Mc];         // per-person pull
    __shared__ float wsum[8];            // per-wave push partials

    const float* tb = tags + (size_t)b * Nc * Tc;
    const int*   kb = kp   + (size_t)b * Mc * Kc * 2;

    // ---- Phase 1: gather (one 32-B vector load per thread, single pass) ----
    if (tid < Mc * Kc) {
        int idx = kb[2 * tid];
        int v   = kb[2 * tid + 1];
        vf[tid] = (v > 0) ? 1.0f : 0.0f;
        const float4* src = (const float4*)(tb + (size_t)idx * Tc);
        float4 a = src[0];
        float4 c = src[1];
        float* gd = g + tid * Tc;
        ((float4*)gd)[0] = a;
        ((float4*)gd)[1] = c;
    }
    __syncthreads();

    // ---- Phase 2a: per-(person, tag-dim) mean; 240 threads ----
    if (tid < Mc * Tc) {
        int m = tid >> 3;
        int t = tid & 7;
        float c = 0.0f, s = 0.0f;
        #pragma unroll
        for (int k = 0; k < Kc; ++k) {
            float v = vf[m * Kc + k];
            c += v;
            s += g[(m * Kc + k) * Tc + t] * v;
        }
        float inv = 1.0f / fmaxf(c, 1.0f);
        mean_s[tid] = s * inv;
        if (t == 0) cnt_s[m] = c;
    }
    __syncthreads();

    // ---- Phase 2b: per-joint squared diff to mean; 510 threads ----
    if (tid < Mc * Kc) {
        int m = tid / Kc;
        float sq = 0.0f;
        #pragma unroll
        for (int t = 0; t < Tc; ++t) {
            float d = g[tid * Tc + t] - mean_s[m * Tc + t];
            sq += d * d;
        }
        sq_s[tid] = sq * 0.125f * vf[tid];   // mean over T=8, masked
    }
    __syncthreads();

    // ---- Phase 2c: per-person pull; 30 threads ----
    if (tid < Mc) {
        float s = 0.0f;
        #pragma unroll
        for (int k = 0; k < Kc; ++k) s += sq_s[tid * Kc + k];
        pull_p[tid] = s / fmaxf(cnt_s[tid], 1.0f);
    }
    // (no barrier needed: phase 3 reads only mean_s/cnt_s, which are ready;
    //  pull_p is read by thread 0 only after the barrier below)

    // ---- Phase 3: push over distinct valid person pairs ----
    float local = 0.0f;
    for (int p = tid; p < Mc * Mc; p += THREADS) {
        int i = p / Mc;
        int j = p - i * Mc;
        if (i != j && cnt_s[i] > 0.0f && cnt_s[j] > 0.0f) {
            float d2 = 0.0f;
            #pragma unroll
            for (int t = 0; t < Tc; ++t) {
                float d = mean_s[i * Tc + t] - mean_s[j * Tc + t];
                d2 += d * d;
            }
            local += expf(-d2);
        }
    }
    #pragma unroll
    for (int off = 32; off > 0; off >>= 1)
        local += __shfl_down(local, off, 64);
    if ((tid & 63) == 0) wsum[tid >> 6] = local;
    __syncthreads();

    if (tid == 0) {
        float push_tot = 0.0f;
        #pragma unroll
        for (int w = 0; w < 8; ++w) push_tot += wsum[w];
        float n = 0.0f, pull = 0.0f;
        for (int m = 0; m < Mc; ++m) {
            n    += (cnt_s[m] > 0.0f) ? 1.0f : 0.0f;
            pull += pull_p[m];
        }
        pull /= fmaxf(n, 1.0f);
        float push = 0.0f;
        if (n > 1.0f)
            push = push_tot / fmaxf(n * (n - 1.0f), 1.0f) * 0.5f;
        out[2 * b + 0] = push;
        out[2 * b + 1] = pull;
    }
}

extern "C" void kernel_launch(void* const* d_in, const int* in_sizes, int n_in,
                              void* d_out, int out_size, void* d_ws, size_t ws_size,
                              hipStream_t stream) {
    const float* tags = (const float*)d_in[0];
    const int*   kp   = (const int*)d_in[1];
    float*       out  = (float*)d_out;
    ae_loss_kernel<<<Bc, THREADS, 0, stream>>>(tags, kp, out);
}